// Round 9
// baseline (560.681 us; speedup 1.0000x reference)
//
#include <hip/hip_runtime.h>

#define N_NODES   100000
#define N_EDGES   3200000
#define NUM_GRAPHS 1024
#define F_IN      128
#define EMB       32

#define NGROUP    256                      // dst buckets
#define GROUP_SZ  391                      // 256*391 = 100096 >= N
#define BCAP      13824                    // mean 12512 + ~11.7 sigma
#define FB        1024                     // fill block threads
#define FILL_ITER 14                       // ceil(BCAP/FB)

#define PART_TILE 8192
#define PART_THREADS 512
#define PART_NB   ((N_EDGES + PART_TILE - 1) / PART_TILE)   // 391

// ---- tiny init: zero bucket counters; rp sentinel ----
__global__ void init_k(int* __restrict__ bucketCnt, int* __restrict__ rp) {
    int i = threadIdx.x;
    if (i < NGROUP) bucketCnt[i] = 0;
    if (i == 0) rp[N_NODES] = N_EDGES;
}

// ---- partition edges into 256 dst-buckets, packed 4B, coalesced nt writes ----
__global__ __launch_bounds__(PART_THREADS) void partition_k(const int* __restrict__ src,
                                                            const int* __restrict__ dst,
                                                            int* __restrict__ bucketCnt,
                                                            unsigned* __restrict__ bEdges) {
    __shared__ unsigned stage[PART_TILE];          // 32 KB
    __shared__ unsigned char bucketOf[PART_TILE];  // 8 KB
    __shared__ int hist[NGROUP];
    __shared__ int lbase[NGROUP + 1];
    __shared__ int gbase[NGROUP];
    int t = threadIdx.x;
    int base = blockIdx.x * PART_TILE;
    for (int k = t; k < NGROUP; k += PART_THREADS) hist[k] = 0;
    __syncthreads();
    unsigned val[16]; int bk[16], rk[16];
#pragma unroll
    for (int i = 0; i < 16; ++i) {
        int e = base + i * PART_THREADS + t;
        bk[i] = -1;
        if (e < N_EDGES) {
            unsigned s = (unsigned)__builtin_nontemporal_load(src + e);
            unsigned d = (unsigned)__builtin_nontemporal_load(dst + e);
            int b = (int)(d / GROUP_SZ);
            val[i] = ((d - (unsigned)b * GROUP_SZ) << 17) | s;
            bk[i] = b;
            rk[i] = atomicAdd(&hist[b], 1);            // LDS atomic
        }
    }
    __syncthreads();
    // exclusive scan of hist -> lbase (Hillis on 256, done by first 256 threads)
    __shared__ int sc[NGROUP];
    if (t < NGROUP) sc[t] = hist[t];
    __syncthreads();
    for (int off = 1; off < NGROUP; off <<= 1) {
        int v = 0;
        if (t < NGROUP) v = sc[t] + ((t >= off) ? sc[t - off] : 0);
        __syncthreads();
        if (t < NGROUP) sc[t] = v;
        __syncthreads();
    }
    if (t < NGROUP) {
        lbase[t] = sc[t] - hist[t];
        if (hist[t] > 0) gbase[t] = atomicAdd(&bucketCnt[t], hist[t]);
        if (t == NGROUP - 1) lbase[NGROUP] = sc[t];
    }
    __syncthreads();
#pragma unroll
    for (int i = 0; i < 16; ++i)
        if (bk[i] >= 0) {
            int j = lbase[bk[i]] + rk[i];
            stage[j] = val[i];
            bucketOf[j] = (unsigned char)bk[i];
        }
    __syncthreads();
    int total = lbase[NGROUP];
    for (int j = t; j < total; j += PART_THREADS) {
        int b = bucketOf[j];                           // direct lookup (no binary search)
        int off = gbase[b] + (j - lbase[b]);
        if (off < BCAP) __builtin_nontemporal_store(stage[j], &bEdges[(size_t)b * BCAP + off]);
    }
}

// ---- one-off: exclusive scan of 256 bucket counts -> global bucketBase ----
__global__ __launch_bounds__(256) void bucketbase_k(const int* __restrict__ bucketCnt,
                                                    int* __restrict__ bucketBase) {
    __shared__ int l[256];
    int t = threadIdx.x;
    int c = bucketCnt[t]; if (c > BCAP) c = BCAP;
    l[t] = c;
    __syncthreads();
    for (int off = 1; off < 256; off <<= 1) {
        int v = l[t] + ((t >= off) ? l[t - off] : 0);
        __syncthreads();
        l[t] = v;
        __syncthreads();
    }
    bucketBase[t] = l[t] - c;                          // exclusive
}

// ---- per-bucket LDS counting sort: writes rp slice, dinv, col (all coalesced) ----
__global__ __launch_bounds__(FB) void fill_k(const unsigned* __restrict__ bEdges,
                                             const int* __restrict__ bucketCnt,
                                             const int* __restrict__ bucketBase,
                                             int* __restrict__ rp,
                                             float* __restrict__ dinv,
                                             int* __restrict__ col) {
    __shared__ int cur[GROUP_SZ];          // per-node cursors
    __shared__ int nodesum[512];
    __shared__ unsigned lout[BCAP];        // 55.3 KB staging for sorted edges
    int b = blockIdx.x, t = threadIdx.x;
    int colBase = bucketBase[b];

    int nb = N_NODES - b * GROUP_SZ; if (nb > GROUP_SZ) nb = GROUP_SZ;
    for (int k = t; k < nb; k += FB) cur[k] = 0;
    __syncthreads();

    int cnt = bucketCnt[b]; if (cnt > BCAP) cnt = BCAP;
    const unsigned* be = bEdges + (size_t)b * BCAP;
    unsigned val[FILL_ITER];
#pragma unroll
    for (int i = 0; i < FILL_ITER; ++i) {
        int idx = i * FB + t;
        val[i] = 0xFFFFFFFFu;
        if (idx < cnt) {
            unsigned v = __builtin_nontemporal_load(be + idx);
            val[i] = v;
            atomicAdd(&cur[v >> 17], 1);               // LDS histogram by local node
        }
    }
    __syncthreads();

    int hc = 0;
    if (t < nb) {
        hc = cur[t];
        nodesum[t] = hc;
        dinv[b * GROUP_SZ + t] = rsqrtf((float)(hc + 1));
    } else if (t < 512) nodesum[t] = 0;
    __syncthreads();
    for (int off = 1; off < 512; off <<= 1) {
        int v = 0;
        if (t < 512) v = nodesum[t] + ((t >= off) ? nodesum[t - off] : 0);
        __syncthreads();
        if (t < 512) nodesum[t] = v;
        __syncthreads();
    }
    if (t < nb) {
        int p = (t > 0) ? nodesum[t - 1] : 0;
        rp[b * GROUP_SZ + t] = colBase + p;
        cur[t] = p;
    }
    __syncthreads();

#pragma unroll
    for (int i = 0; i < FILL_ITER; ++i) {
        unsigned v = val[i];
        if (v != 0xFFFFFFFFu) {
            int slot = atomicAdd(&cur[v >> 17], 1);
            lout[slot] = v & 0x1FFFFu;
        }
    }
    __syncthreads();

    for (int i = t; i < cnt; i += FB)
        __builtin_nontemporal_store((int)lout[i], col + colBase + i);
}

// ---- layer 0 transform, register-blocked: thread = (8-node group, channel quad) ----
__global__ __launch_bounds__(256) void transform0_k(const float* __restrict__ x,
                                                    const float* __restrict__ W0,
                                                    const float* __restrict__ dinv,
                                                    float4* __restrict__ tmp4) {
    int i = blockIdx.x * blockDim.x + threadIdx.x;   // 100000 threads
    if (i >= (N_NODES / 8) * 8) return;
    int gid = i >> 3, q = i & 7;
    int n0 = gid * 8;
    const float* wq = W0 + q * 4;
    float4 acc[8];
#pragma unroll
    for (int j = 0; j < 8; ++j) acc[j] = make_float4(0.f, 0.f, 0.f, 0.f);
#pragma unroll 2
    for (int kc = 0; kc < F_IN / 4; ++kc) {
        float4 w0 = *(const float4*)(wq + (kc * 4 + 0) * EMB);
        float4 w1 = *(const float4*)(wq + (kc * 4 + 1) * EMB);
        float4 w2 = *(const float4*)(wq + (kc * 4 + 2) * EMB);
        float4 w3 = *(const float4*)(wq + (kc * 4 + 3) * EMB);
#pragma unroll
        for (int j = 0; j < 8; ++j) {
            float4 xv = *(const float4*)(x + (long long)(n0 + j) * F_IN + kc * 4);
            acc[j].x += xv.x * w0.x; acc[j].y += xv.x * w0.y; acc[j].z += xv.x * w0.z; acc[j].w += xv.x * w0.w;
            acc[j].x += xv.y * w1.x; acc[j].y += xv.y * w1.y; acc[j].z += xv.y * w1.z; acc[j].w += xv.y * w1.w;
            acc[j].x += xv.z * w2.x; acc[j].y += xv.z * w2.y; acc[j].z += xv.z * w2.z; acc[j].w += xv.z * w2.w;
            acc[j].x += xv.w * w3.x; acc[j].y += xv.w * w3.y; acc[j].z += xv.w * w3.z; acc[j].w += xv.w * w3.w;
        }
    }
#pragma unroll
    for (int j = 0; j < 8; ++j) {
        float dn = dinv[n0 + j];
        acc[j].x *= dn; acc[j].y *= dn; acc[j].z *= dn; acc[j].w *= dn;
        tmp4[(n0 + j) * 8 + q] = acc[j];
    }
}

// ---- fused gather (+ optional next-layer transform in LDS) ----
// FUSE=1: out4 = tmp_next = (leaky(agg*dinv+bias) @ W) * dinv
// FUSE=0: out4 = h = leaky(agg*dinv+bias)
template <bool FUSE>
__global__ __launch_bounds__(256) void gather_k(const int* __restrict__ rp,
                                                const int* __restrict__ col,
                                                const float4* __restrict__ tmp4,
                                                const float* __restrict__ dinv,
                                                const float* __restrict__ bias,
                                                const float* __restrict__ W,
                                                float4* __restrict__ out4) {
    __shared__ float4 Wl[256];        // W[32][32] as [k*8+q]
    __shared__ float4 hx[32 * 9];     // 32 nodes x 8 quads, padded row=9 (bank-safe)
    int t = threadIdx.x;
    int i = blockIdx.x * 256 + t;     // grid exact: 3125 blocks
    int n = i >> 3, q = i & 7, ln = t >> 3;
    if (FUSE) Wl[t] = ((const float4*)W)[t];

    float4 acc = tmp4[i];             // self-loop term
    int k = rp[n], end = rp[n + 1];
    for (; k < end && (k & 3); ++k) {
        float4 v = tmp4[col[k] * 8 + q];
        acc.x += v.x; acc.y += v.y; acc.z += v.z; acc.w += v.w;
    }
    for (; k + 8 <= end; k += 8) {
        int4 c0 = *(const int4*)(col + k);
        int4 c1 = *(const int4*)(col + k + 4);
        float4 v0 = tmp4[c0.x * 8 + q], v1 = tmp4[c0.y * 8 + q];
        float4 v2 = tmp4[c0.z * 8 + q], v3 = tmp4[c0.w * 8 + q];
        float4 v4 = tmp4[c1.x * 8 + q], v5 = tmp4[c1.y * 8 + q];
        float4 v6 = tmp4[c1.z * 8 + q], v7 = tmp4[c1.w * 8 + q];
        acc.x += ((v0.x + v1.x) + (v2.x + v3.x)) + ((v4.x + v5.x) + (v6.x + v7.x));
        acc.y += ((v0.y + v1.y) + (v2.y + v3.y)) + ((v4.y + v5.y) + (v6.y + v7.y));
        acc.z += ((v0.z + v1.z) + (v2.z + v3.z)) + ((v4.z + v5.z) + (v6.z + v7.z));
        acc.w += ((v0.w + v1.w) + (v2.w + v3.w)) + ((v4.w + v5.w) + (v6.w + v7.w));
    }
    for (; k + 4 <= end; k += 4) {
        int4 c0 = *(const int4*)(col + k);
        float4 v0 = tmp4[c0.x * 8 + q], v1 = tmp4[c0.y * 8 + q];
        float4 v2 = tmp4[c0.z * 8 + q], v3 = tmp4[c0.w * 8 + q];
        acc.x += (v0.x + v1.x) + (v2.x + v3.x);
        acc.y += (v0.y + v1.y) + (v2.y + v3.y);
        acc.z += (v0.z + v1.z) + (v2.z + v3.z);
        acc.w += (v0.w + v1.w) + (v2.w + v3.w);
    }
    for (; k < end; ++k) {
        float4 v = tmp4[col[k] * 8 + q];
        acc.x += v.x; acc.y += v.y; acc.z += v.z; acc.w += v.w;
    }
    float dn = dinv[n];
    float4 bb = ((const float4*)bias)[q];
    float4 rr;
    rr.x = acc.x * dn + bb.x;
    rr.y = acc.y * dn + bb.y;
    rr.z = acc.z * dn + bb.z;
    rr.w = acc.w * dn + bb.w;
    rr.x = rr.x > 0.f ? rr.x : 0.01f * rr.x;
    rr.y = rr.y > 0.f ? rr.y : 0.01f * rr.y;
    rr.z = rr.z > 0.f ? rr.z : 0.01f * rr.z;
    rr.w = rr.w > 0.f ? rr.w : 0.01f * rr.w;

    if (!FUSE) {
        out4[i] = rr;
        return;
    }
    // exchange h quads among the 8 lanes of this node, multiply by W
    hx[ln * 9 + q] = rr;
    __syncthreads();
    float4 tq = make_float4(0.f, 0.f, 0.f, 0.f);
#pragma unroll
    for (int kq = 0; kq < 8; ++kq) {
        float4 hv = hx[ln * 9 + kq];
        float4 w0 = Wl[(kq * 4 + 0) * 8 + q];
        float4 w1 = Wl[(kq * 4 + 1) * 8 + q];
        float4 w2 = Wl[(kq * 4 + 2) * 8 + q];
        float4 w3 = Wl[(kq * 4 + 3) * 8 + q];
        tq.x += hv.x * w0.x; tq.y += hv.x * w0.y; tq.z += hv.x * w0.z; tq.w += hv.x * w0.w;
        tq.x += hv.y * w1.x; tq.y += hv.y * w1.y; tq.z += hv.y * w1.z; tq.w += hv.y * w1.w;
        tq.x += hv.z * w2.x; tq.y += hv.z * w2.y; tq.z += hv.z * w2.z; tq.w += hv.z * w2.w;
        tq.x += hv.w * w3.x; tq.y += hv.w * w3.y; tq.z += hv.w * w3.z; tq.w += hv.w * w3.w;
    }
    tq.x *= dn; tq.y *= dn; tq.z *= dn; tq.w *= dn;
    out4[i] = tq;
}

// ---- fused pool + head (batch_index sorted) ----
__global__ __launch_bounds__(256) void pool_head_k(const float* __restrict__ h,
                                                   const int* __restrict__ batch,
                                                   const float* __restrict__ Wout,
                                                   const float* __restrict__ bout,
                                                   float* __restrict__ out) {
    int g = blockIdx.x;
    __shared__ int sbeg, send;
    if (threadIdx.x == 0) {
        int lo = 0, hi = N_NODES;
        while (lo < hi) { int mid = (lo + hi) >> 1; if (batch[mid] < g) lo = mid + 1; else hi = mid; }
        sbeg = lo;
        hi = N_NODES;
        while (lo < hi) { int mid = (lo + hi) >> 1; if (batch[mid] < g + 1) lo = mid + 1; else hi = mid; }
        send = lo;
    }
    __syncthreads();
    int beg = sbeg, end = send;
    int t = threadIdx.x, c = t & 31, r = t >> 5;
    float m = -INFINITY;
    for (int n = beg + r; n < end; n += 8) m = fmaxf(m, h[n * EMB + c]);
    __shared__ float red[256];
    red[t] = m;
    __syncthreads();
    if (t < 128) red[t] = fmaxf(red[t], red[t + 128]);
    __syncthreads();
    if (t < 64) red[t] = fmaxf(red[t], red[t + 64]);
    __syncthreads();
    if (t < 32) {
        m = fmaxf(red[t], red[t + 32]);
        out[NUM_GRAPHS + g * EMB + c] = m;
        float p = m * Wout[c];
#pragma unroll
        for (int o = 16; o > 0; o >>= 1) p += __shfl_xor(p, o, 32);
        if (c == 0) out[g] = p + bout[0];
    }
}

extern "C" void kernel_launch(void* const* d_in, const int* in_sizes, int n_in,
                              void* d_out, int out_size, void* d_ws, size_t ws_size,
                              hipStream_t stream) {
    const float* x     = (const float*)d_in[0];
    const int*   ei    = (const int*)d_in[1];
    const int*   src   = ei;
    const int*   dst   = ei + N_EDGES;
    const int*   batch = (const int*)d_in[2];
    const float* W0    = (const float*)d_in[3];
    const float* b0    = (const float*)d_in[4];
    const float* Ws    = (const float*)d_in[5];
    const float* bs    = (const float*)d_in[6];
    const float* Wout  = (const float*)d_in[7];
    const float* bout  = (const float*)d_in[8];
    float* out = (float*)d_out;

    char* ws = (char*)d_ws;
    int*   rp        = (int*)ws;   ws += (size_t)(N_NODES + 4) * 4;     // 400 KB
    int*   col       = (int*)ws;   ws += (size_t)N_EDGES * 4;           // 12.8 MB
    float* dinv      = (float*)ws; ws += (size_t)N_NODES * 4;           // 400 KB
    float* tmp       = (float*)ws; ws += (size_t)N_NODES * EMB * 4;     // 12.8 MB
    float* h         = (float*)ws; ws += (size_t)N_NODES * EMB * 4;     // 12.8 MB
    int*   bucketCnt = (int*)ws;   ws += 1024;                          // 256 ints
    int*   bucketBase= (int*)ws;   ws += 1024;                          // 256 ints
    unsigned* bEdges = (unsigned*)tmp;   // 14.2 MB alias over tmp+h, dead before transforms

    const int B = 256;
    const int G8_g = (N_NODES * 8) / B;                  // 3125 exact
    const int T_g  = (N_NODES + B - 1) / B;              // 391

    init_k<<<1, B, 0, stream>>>(bucketCnt, rp);
    partition_k<<<PART_NB, PART_THREADS, 0, stream>>>(src, dst, bucketCnt, bEdges);
    bucketbase_k<<<1, 256, 0, stream>>>(bucketCnt, bucketBase);
    fill_k<<<NGROUP, FB, 0, stream>>>(bEdges, bucketCnt, bucketBase, rp, dinv, col);

    // layer 0 transform
    transform0_k<<<T_g, B, 0, stream>>>(x, W0, dinv, (float4*)tmp);
    // gathers: layers 0..2 fuse the next transform; layer 3 writes h
    gather_k<true ><<<G8_g, B, 0, stream>>>(rp, col, (const float4*)tmp, dinv, b0,          Ws + 0 * 1024, (float4*)h);
    gather_k<true ><<<G8_g, B, 0, stream>>>(rp, col, (const float4*)h,   dinv, bs + 0 * EMB, Ws + 1 * 1024, (float4*)tmp);
    gather_k<true ><<<G8_g, B, 0, stream>>>(rp, col, (const float4*)tmp, dinv, bs + 1 * EMB, Ws + 2 * 1024, (float4*)h);
    gather_k<false><<<G8_g, B, 0, stream>>>(rp, col, (const float4*)h,   dinv, bs + 2 * EMB, nullptr,       (float4*)tmp);

    pool_head_k<<<NUM_GRAPHS, B, 0, stream>>>(tmp, batch, Wout, bout, out);
}

// Round 10
// 558.251 us; speedup vs baseline: 1.0044x; 1.0044x over previous
//
#include <hip/hip_runtime.h>

#define N_NODES   100000
#define N_EDGES   3200000
#define NUM_GRAPHS 1024
#define F_IN      128
#define EMB       32

#define NGROUP    256                      // dst buckets
#define GROUP_SZ  391                      // 256*391 = 100096 >= N
#define BCAP      13824                    // mean 12512 + ~11.7 sigma
#define FB        1024                     // fill block threads
#define FILL_ITER 14                       // ceil(BCAP/FB)

#define PART_TILE 8192
#define PART_THREADS 512
#define PART_NB   ((N_EDGES + PART_TILE - 1) / PART_TILE)   // 391

// ---- tiny init: zero bucket counters; rp sentinel ----
__global__ void init_k(int* __restrict__ bucketCnt, int* __restrict__ rp) {
    int i = threadIdx.x;
    if (i < NGROUP) bucketCnt[i] = 0;
    if (i == 0) rp[N_NODES] = N_EDGES;
}

// ---- partition edges into 256 dst-buckets, packed 4B, coalesced nt writes ----
__global__ __launch_bounds__(PART_THREADS) void partition_k(const int* __restrict__ src,
                                                            const int* __restrict__ dst,
                                                            int* __restrict__ bucketCnt,
                                                            unsigned* __restrict__ bEdges) {
    __shared__ unsigned stage[PART_TILE];          // 32 KB
    __shared__ unsigned char bucketOf[PART_TILE];  // 8 KB
    __shared__ int hist[NGROUP];
    __shared__ int lbase[NGROUP + 1];
    __shared__ int gbase[NGROUP];
    int t = threadIdx.x;
    int base = blockIdx.x * PART_TILE;
    for (int k = t; k < NGROUP; k += PART_THREADS) hist[k] = 0;
    __syncthreads();
    unsigned val[16]; int bk[16], rk[16];
#pragma unroll
    for (int i = 0; i < 16; ++i) {
        int e = base + i * PART_THREADS + t;
        bk[i] = -1;
        if (e < N_EDGES) {
            unsigned s = (unsigned)__builtin_nontemporal_load(src + e);
            unsigned d = (unsigned)__builtin_nontemporal_load(dst + e);
            int b = (int)(d / GROUP_SZ);
            val[i] = ((d - (unsigned)b * GROUP_SZ) << 17) | s;
            bk[i] = b;
            rk[i] = atomicAdd(&hist[b], 1);            // LDS atomic
        }
    }
    __syncthreads();
    __shared__ int sc[NGROUP];
    if (t < NGROUP) sc[t] = hist[t];
    __syncthreads();
    for (int off = 1; off < NGROUP; off <<= 1) {
        int v = 0;
        if (t < NGROUP) v = sc[t] + ((t >= off) ? sc[t - off] : 0);
        __syncthreads();
        if (t < NGROUP) sc[t] = v;
        __syncthreads();
    }
    if (t < NGROUP) {
        lbase[t] = sc[t] - hist[t];
        if (hist[t] > 0) gbase[t] = atomicAdd(&bucketCnt[t], hist[t]);
        if (t == NGROUP - 1) lbase[NGROUP] = sc[t];
    }
    __syncthreads();
#pragma unroll
    for (int i = 0; i < 16; ++i)
        if (bk[i] >= 0) {
            int j = lbase[bk[i]] + rk[i];
            stage[j] = val[i];
            bucketOf[j] = (unsigned char)bk[i];
        }
    __syncthreads();
    int total = lbase[NGROUP];
    for (int j = t; j < total; j += PART_THREADS) {
        int b = bucketOf[j];                           // direct lookup
        int off = gbase[b] + (j - lbase[b]);
        if (off < BCAP) __builtin_nontemporal_store(stage[j], &bEdges[(size_t)b * BCAP + off]);
    }
}

// ---- one-off: exclusive scan of 256 bucket counts -> global bucketBase ----
__global__ __launch_bounds__(256) void bucketbase_k(const int* __restrict__ bucketCnt,
                                                    int* __restrict__ bucketBase) {
    __shared__ int l[256];
    int t = threadIdx.x;
    int c = bucketCnt[t]; if (c > BCAP) c = BCAP;
    l[t] = c;
    __syncthreads();
    for (int off = 1; off < 256; off <<= 1) {
        int v = l[t] + ((t >= off) ? l[t - off] : 0);
        __syncthreads();
        l[t] = v;
        __syncthreads();
    }
    bucketBase[t] = l[t] - c;                          // exclusive
}

// ---- per-bucket LDS counting sort: writes rp slice, dinv, col (all coalesced) ----
__global__ __launch_bounds__(FB) void fill_k(const unsigned* __restrict__ bEdges,
                                             const int* __restrict__ bucketCnt,
                                             const int* __restrict__ bucketBase,
                                             int* __restrict__ rp,
                                             float* __restrict__ dinv,
                                             int* __restrict__ col) {
    __shared__ int cur[GROUP_SZ];          // per-node cursors
    __shared__ int nodesum[512];
    __shared__ unsigned lout[BCAP];        // 55.3 KB staging
    int b = blockIdx.x, t = threadIdx.x;
    int colBase = bucketBase[b];

    int nb = N_NODES - b * GROUP_SZ; if (nb > GROUP_SZ) nb = GROUP_SZ;
    for (int k = t; k < nb; k += FB) cur[k] = 0;
    __syncthreads();

    int cnt = bucketCnt[b]; if (cnt > BCAP) cnt = BCAP;
    const unsigned* be = bEdges + (size_t)b * BCAP;
    unsigned val[FILL_ITER];
#pragma unroll
    for (int i = 0; i < FILL_ITER; ++i) {
        int idx = i * FB + t;
        val[i] = 0xFFFFFFFFu;
        if (idx < cnt) {
            unsigned v = __builtin_nontemporal_load(be + idx);
            val[i] = v;
            atomicAdd(&cur[v >> 17], 1);               // LDS histogram by local node
        }
    }
    __syncthreads();

    int hc = 0;
    if (t < nb) {
        hc = cur[t];
        nodesum[t] = hc;
        dinv[b * GROUP_SZ + t] = rsqrtf((float)(hc + 1));
    } else if (t < 512) nodesum[t] = 0;
    __syncthreads();
    for (int off = 1; off < 512; off <<= 1) {
        int v = 0;
        if (t < 512) v = nodesum[t] + ((t >= off) ? nodesum[t - off] : 0);
        __syncthreads();
        if (t < 512) nodesum[t] = v;
        __syncthreads();
    }
    if (t < nb) {
        int p = (t > 0) ? nodesum[t - 1] : 0;
        rp[b * GROUP_SZ + t] = colBase + p;
        cur[t] = p;
    }
    __syncthreads();

#pragma unroll
    for (int i = 0; i < FILL_ITER; ++i) {
        unsigned v = val[i];
        if (v != 0xFFFFFFFFu) {
            int slot = atomicAdd(&cur[v >> 17], 1);
            lout[slot] = v & 0x1FFFFu;
        }
    }
    __syncthreads();

    for (int i = t; i < cnt; i += FB)
        __builtin_nontemporal_store((int)lout[i], col + colBase + i);
}

// ---- layer 0 transform, register-blocked: thread = (8-node group, channel quad) ----
__global__ __launch_bounds__(256) void transform0_k(const float* __restrict__ x,
                                                    const float* __restrict__ W0,
                                                    const float* __restrict__ dinv,
                                                    float4* __restrict__ tmp4) {
    int i = blockIdx.x * blockDim.x + threadIdx.x;   // 100000 threads
    if (i >= (N_NODES / 8) * 8) return;
    int gid = i >> 3, q = i & 7;
    int n0 = gid * 8;
    const float* wq = W0 + q * 4;
    float4 acc[8];
#pragma unroll
    for (int j = 0; j < 8; ++j) acc[j] = make_float4(0.f, 0.f, 0.f, 0.f);
#pragma unroll 2
    for (int kc = 0; kc < F_IN / 4; ++kc) {
        float4 w0 = *(const float4*)(wq + (kc * 4 + 0) * EMB);
        float4 w1 = *(const float4*)(wq + (kc * 4 + 1) * EMB);
        float4 w2 = *(const float4*)(wq + (kc * 4 + 2) * EMB);
        float4 w3 = *(const float4*)(wq + (kc * 4 + 3) * EMB);
#pragma unroll
        for (int j = 0; j < 8; ++j) {
            float4 xv = *(const float4*)(x + (long long)(n0 + j) * F_IN + kc * 4);
            acc[j].x += xv.x * w0.x; acc[j].y += xv.x * w0.y; acc[j].z += xv.x * w0.z; acc[j].w += xv.x * w0.w;
            acc[j].x += xv.y * w1.x; acc[j].y += xv.y * w1.y; acc[j].z += xv.y * w1.z; acc[j].w += xv.y * w1.w;
            acc[j].x += xv.z * w2.x; acc[j].y += xv.z * w2.y; acc[j].z += xv.z * w2.z; acc[j].w += xv.z * w2.w;
            acc[j].x += xv.w * w3.x; acc[j].y += xv.w * w3.y; acc[j].z += xv.w * w3.z; acc[j].w += xv.w * w3.w;
        }
    }
#pragma unroll
    for (int j = 0; j < 8; ++j) {
        float dn = dinv[n0 + j];
        acc[j].x *= dn; acc[j].y *= dn; acc[j].z *= dn; acc[j].w *= dn;
        tmp4[(n0 + j) * 8 + q] = acc[j];
    }
}

// ---- fused gather (+ optional next-layer transform, wave-synchronous LDS exchange) ----
// FUSE=1: out4 = tmp_next = (leaky(agg*dinv+bias) @ W) * dinv
// FUSE=0: out4 = h = leaky(agg*dinv+bias)
// NOTE: the h-exchange is intra-wave (node t>>3's 8 quads live in lanes (t&~7)+0..7),
// so NO __syncthreads() — R9's barrier convoyed the block's waves and tripled FETCH.
template <bool FUSE>
__global__ __launch_bounds__(256) void gather_k(const int* __restrict__ rp,
                                                const int* __restrict__ col,
                                                const float4* __restrict__ tmp4,
                                                const float* __restrict__ dinv,
                                                const float* __restrict__ bias,
                                                const float* __restrict__ W,
                                                float4* __restrict__ out4) {
    __shared__ float4 Wl[256];        // W[32][32] as [k*8+q]
    __shared__ float4 hx[32 * 9];     // 32 nodes x 8 quads, padded row=9
    int t = threadIdx.x;
    int i = blockIdx.x * 256 + t;     // grid exact: 3125 blocks
    int n = i >> 3, q = i & 7, ln = t >> 3;
    if (FUSE) Wl[t] = ((const float4*)W)[t];   // cross-wave read OK: same data every wave reads what any wave wrote? NO — each thread reads only Wl[...] below after writing its own? (see note)
    // Note: Wl[t] is written by thread t and read as Wl[(kq*4+m)*8+q] — cross-wave.
    // Safe without a barrier ONLY because every wave writes its own quarter before
    // any wave can read it? Not guaranteed -> make W reads wave-local instead:
    // each lane re-reads W rows it needs directly via Wl written by its own wave is
    // NOT assured; so for FUSE we barrier ONCE for Wl (cheap, before edge loop),
    // keeping the h-exchange barrier-free.
    if (FUSE) __syncthreads();        // one early barrier (no work-imbalance convoy here)

    float4 acc = tmp4[i];             // self-loop term
    int k = rp[n], end = rp[n + 1];
    for (; k < end && (k & 3); ++k) {
        float4 v = tmp4[col[k] * 8 + q];
        acc.x += v.x; acc.y += v.y; acc.z += v.z; acc.w += v.w;
    }
    for (; k + 8 <= end; k += 8) {
        int4 c0 = *(const int4*)(col + k);
        int4 c1 = *(const int4*)(col + k + 4);
        float4 v0 = tmp4[c0.x * 8 + q], v1 = tmp4[c0.y * 8 + q];
        float4 v2 = tmp4[c0.z * 8 + q], v3 = tmp4[c0.w * 8 + q];
        float4 v4 = tmp4[c1.x * 8 + q], v5 = tmp4[c1.y * 8 + q];
        float4 v6 = tmp4[c1.z * 8 + q], v7 = tmp4[c1.w * 8 + q];
        acc.x += ((v0.x + v1.x) + (v2.x + v3.x)) + ((v4.x + v5.x) + (v6.x + v7.x));
        acc.y += ((v0.y + v1.y) + (v2.y + v3.y)) + ((v4.y + v5.y) + (v6.y + v7.y));
        acc.z += ((v0.z + v1.z) + (v2.z + v3.z)) + ((v4.z + v5.z) + (v6.z + v7.z));
        acc.w += ((v0.w + v1.w) + (v2.w + v3.w)) + ((v4.w + v5.w) + (v6.w + v7.w));
    }
    for (; k + 4 <= end; k += 4) {
        int4 c0 = *(const int4*)(col + k);
        float4 v0 = tmp4[c0.x * 8 + q], v1 = tmp4[c0.y * 8 + q];
        float4 v2 = tmp4[c0.z * 8 + q], v3 = tmp4[c0.w * 8 + q];
        acc.x += (v0.x + v1.x) + (v2.x + v3.x);
        acc.y += (v0.y + v1.y) + (v2.y + v3.y);
        acc.z += (v0.z + v1.z) + (v2.z + v3.z);
        acc.w += (v0.w + v1.w) + (v2.w + v3.w);
    }
    for (; k < end; ++k) {
        float4 v = tmp4[col[k] * 8 + q];
        acc.x += v.x; acc.y += v.y; acc.z += v.z; acc.w += v.w;
    }
    float dn = dinv[n];
    float4 bb = ((const float4*)bias)[q];
    float4 rr;
    rr.x = acc.x * dn + bb.x;
    rr.y = acc.y * dn + bb.y;
    rr.z = acc.z * dn + bb.z;
    rr.w = acc.w * dn + bb.w;
    rr.x = rr.x > 0.f ? rr.x : 0.01f * rr.x;
    rr.y = rr.y > 0.f ? rr.y : 0.01f * rr.y;
    rr.z = rr.z > 0.f ? rr.z : 0.01f * rr.z;
    rr.w = rr.w > 0.f ? rr.w : 0.01f * rr.w;

    if (!FUSE) {
        out4[i] = rr;
        return;
    }
    // wave-synchronous h-exchange among the 8 lanes of this node (NO block barrier)
    hx[ln * 9 + q] = rr;
    __builtin_amdgcn_wave_barrier();   // compiler fence; HW wave lockstep + lgkmcnt handles the rest
    float4 tq = make_float4(0.f, 0.f, 0.f, 0.f);
#pragma unroll
    for (int kq = 0; kq < 8; ++kq) {
        float4 hv = hx[ln * 9 + kq];
        float4 w0 = Wl[(kq * 4 + 0) * 8 + q];
        float4 w1 = Wl[(kq * 4 + 1) * 8 + q];
        float4 w2 = Wl[(kq * 4 + 2) * 8 + q];
        float4 w3 = Wl[(kq * 4 + 3) * 8 + q];
        tq.x += hv.x * w0.x; tq.y += hv.x * w0.y; tq.z += hv.x * w0.z; tq.w += hv.x * w0.w;
        tq.x += hv.y * w1.x; tq.y += hv.y * w1.y; tq.z += hv.y * w1.z; tq.w += hv.y * w1.w;
        tq.x += hv.z * w2.x; tq.y += hv.z * w2.y; tq.z += hv.z * w2.z; tq.w += hv.z * w2.w;
        tq.x += hv.w * w3.x; tq.y += hv.w * w3.y; tq.z += hv.w * w3.z; tq.w += hv.w * w3.w;
    }
    tq.x *= dn; tq.y *= dn; tq.z *= dn; tq.w *= dn;
    out4[i] = tq;
}

// ---- fused pool + head (batch_index sorted) ----
__global__ __launch_bounds__(256) void pool_head_k(const float* __restrict__ h,
                                                   const int* __restrict__ batch,
                                                   const float* __restrict__ Wout,
                                                   const float* __restrict__ bout,
                                                   float* __restrict__ out) {
    int g = blockIdx.x;
    __shared__ int sbeg, send;
    if (threadIdx.x == 0) {
        int lo = 0, hi = N_NODES;
        while (lo < hi) { int mid = (lo + hi) >> 1; if (batch[mid] < g) lo = mid + 1; else hi = mid; }
        sbeg = lo;
        hi = N_NODES;
        while (lo < hi) { int mid = (lo + hi) >> 1; if (batch[mid] < g + 1) lo = mid + 1; else hi = mid; }
        send = lo;
    }
    __syncthreads();
    int beg = sbeg, end = send;
    int t = threadIdx.x, c = t & 31, r = t >> 5;
    float m = -INFINITY;
    for (int n = beg + r; n < end; n += 8) m = fmaxf(m, h[n * EMB + c]);
    __shared__ float red[256];
    red[t] = m;
    __syncthreads();
    if (t < 128) red[t] = fmaxf(red[t], red[t + 128]);
    __syncthreads();
    if (t < 64) red[t] = fmaxf(red[t], red[t + 64]);
    __syncthreads();
    if (t < 32) {
        m = fmaxf(red[t], red[t + 32]);
        out[NUM_GRAPHS + g * EMB + c] = m;
        float p = m * Wout[c];
#pragma unroll
        for (int o = 16; o > 0; o >>= 1) p += __shfl_xor(p, o, 32);
        if (c == 0) out[g] = p + bout[0];
    }
}

extern "C" void kernel_launch(void* const* d_in, const int* in_sizes, int n_in,
                              void* d_out, int out_size, void* d_ws, size_t ws_size,
                              hipStream_t stream) {
    const float* x     = (const float*)d_in[0];
    const int*   ei    = (const int*)d_in[1];
    const int*   src   = ei;
    const int*   dst   = ei + N_EDGES;
    const int*   batch = (const int*)d_in[2];
    const float* W0    = (const float*)d_in[3];
    const float* b0    = (const float*)d_in[4];
    const float* Ws    = (const float*)d_in[5];
    const float* bs    = (const float*)d_in[6];
    const float* Wout  = (const float*)d_in[7];
    const float* bout  = (const float*)d_in[8];
    float* out = (float*)d_out;

    char* ws = (char*)d_ws;
    int*   rp        = (int*)ws;   ws += (size_t)(N_NODES + 4) * 4;     // 400 KB
    int*   col       = (int*)ws;   ws += (size_t)N_EDGES * 4;           // 12.8 MB
    float* dinv      = (float*)ws; ws += (size_t)N_NODES * 4;           // 400 KB
    float* tmp       = (float*)ws; ws += (size_t)N_NODES * EMB * 4;     // 12.8 MB
    float* h         = (float*)ws; ws += (size_t)N_NODES * EMB * 4;     // 12.8 MB
    int*   bucketCnt = (int*)ws;   ws += 1024;                          // 256 ints
    int*   bucketBase= (int*)ws;   ws += 1024;                          // 256 ints
    unsigned* bEdges = (unsigned*)tmp;   // 14.2 MB alias over tmp+h, dead before transforms

    const int B = 256;
    const int G8_g = (N_NODES * 8) / B;                  // 3125 exact
    const int T_g  = (N_NODES + B - 1) / B;              // 391

    init_k<<<1, B, 0, stream>>>(bucketCnt, rp);
    partition_k<<<PART_NB, PART_THREADS, 0, stream>>>(src, dst, bucketCnt, bEdges);
    bucketbase_k<<<1, 256, 0, stream>>>(bucketCnt, bucketBase);
    fill_k<<<NGROUP, FB, 0, stream>>>(bEdges, bucketCnt, bucketBase, rp, dinv, col);

    // layer 0 transform
    transform0_k<<<T_g, B, 0, stream>>>(x, W0, dinv, (float4*)tmp);
    // gathers: layers 0..2 fuse the next transform; layer 3 writes h
    gather_k<true ><<<G8_g, B, 0, stream>>>(rp, col, (const float4*)tmp, dinv, b0,           Ws + 0 * 1024, (float4*)h);
    gather_k<true ><<<G8_g, B, 0, stream>>>(rp, col, (const float4*)h,   dinv, bs + 0 * EMB, Ws + 1 * 1024, (float4*)tmp);
    gather_k<true ><<<G8_g, B, 0, stream>>>(rp, col, (const float4*)tmp, dinv, bs + 1 * EMB, Ws + 2 * 1024, (float4*)h);
    gather_k<false><<<G8_g, B, 0, stream>>>(rp, col, (const float4*)h,   dinv, bs + 2 * EMB, nullptr,       (float4*)tmp);

    pool_head_k<<<NUM_GRAPHS, B, 0, stream>>>(tmp, batch, Wout, bout, out);
}

// Round 11
// 449.057 us; speedup vs baseline: 1.2486x; 1.2432x over previous
//
#include <hip/hip_runtime.h>

#define N_NODES   100000
#define N_EDGES   3200000
#define NUM_GRAPHS 1024
#define F_IN      128
#define EMB       32

#define NRANGE    4
#define RANGE_SZ  25000                    // src ranges: 3.2 MB tmp slice fits XCD L2
#define NKEY      (N_NODES * NRANGE)       // 400000 CSR keys

#define NGROUP    256                      // dst buckets
#define GROUP_SZ  391                      // 256*391 = 100096 >= N
#define BCAP      13824                    // mean 12512 + ~11.7 sigma
#define FB        1024                     // fill block threads
#define FILL_ITER 14                       // ceil(BCAP/FB)

#define PART_TILE 8192
#define PART_THREADS 512
#define PART_NB   ((N_EDGES + PART_TILE - 1) / PART_TILE)   // 391

// ---- tiny init: zero bucket counters; rp2 sentinel ----
__global__ void init_k(int* __restrict__ bucketCnt, int* __restrict__ rp2) {
    int i = threadIdx.x;
    if (i < NGROUP) bucketCnt[i] = 0;
    if (i == 0) rp2[NKEY] = N_EDGES;
}

// ---- partition edges into 256 dst-buckets, packed 4B, coalesced nt writes ----
__global__ __launch_bounds__(PART_THREADS) void partition_k(const int* __restrict__ src,
                                                            const int* __restrict__ dst,
                                                            int* __restrict__ bucketCnt,
                                                            unsigned* __restrict__ bEdges) {
    __shared__ unsigned stage[PART_TILE];          // 32 KB
    __shared__ unsigned char bucketOf[PART_TILE];  // 8 KB
    __shared__ int hist[NGROUP];
    __shared__ int lbase[NGROUP + 1];
    __shared__ int gbase[NGROUP];
    __shared__ int sc[NGROUP];
    int t = threadIdx.x;
    int base = blockIdx.x * PART_TILE;
    for (int k = t; k < NGROUP; k += PART_THREADS) hist[k] = 0;
    __syncthreads();
    unsigned val[16]; int bk[16], rk[16];
#pragma unroll
    for (int i = 0; i < 16; ++i) {
        int e = base + i * PART_THREADS + t;
        bk[i] = -1;
        if (e < N_EDGES) {
            unsigned s = (unsigned)__builtin_nontemporal_load(src + e);
            unsigned d = (unsigned)__builtin_nontemporal_load(dst + e);
            int b = (int)(d / GROUP_SZ);
            val[i] = ((d - (unsigned)b * GROUP_SZ) << 17) | s;
            bk[i] = b;
            rk[i] = atomicAdd(&hist[b], 1);            // LDS atomic
        }
    }
    __syncthreads();
    if (t < NGROUP) sc[t] = hist[t];
    __syncthreads();
    for (int off = 1; off < NGROUP; off <<= 1) {
        int v = 0;
        if (t < NGROUP) v = sc[t] + ((t >= off) ? sc[t - off] : 0);
        __syncthreads();
        if (t < NGROUP) sc[t] = v;
        __syncthreads();
    }
    if (t < NGROUP) {
        lbase[t] = sc[t] - hist[t];
        if (hist[t] > 0) gbase[t] = atomicAdd(&bucketCnt[t], hist[t]);
        if (t == NGROUP - 1) lbase[NGROUP] = sc[t];
    }
    __syncthreads();
#pragma unroll
    for (int i = 0; i < 16; ++i)
        if (bk[i] >= 0) {
            int j = lbase[bk[i]] + rk[i];
            stage[j] = val[i];
            bucketOf[j] = (unsigned char)bk[i];
        }
    __syncthreads();
    int total = lbase[NGROUP];
    for (int j = t; j < total; j += PART_THREADS) {
        int b = bucketOf[j];                           // direct lookup
        int off = gbase[b] + (j - lbase[b]);
        if (off < BCAP) __builtin_nontemporal_store(stage[j], &bEdges[(size_t)b * BCAP + off]);
    }
}

// ---- one-off: exclusive scan of 256 bucket counts -> global bucketBase ----
__global__ __launch_bounds__(256) void bucketbase_k(const int* __restrict__ bucketCnt,
                                                    int* __restrict__ bucketBase) {
    __shared__ int l[256];
    int t = threadIdx.x;
    int c = bucketCnt[t]; if (c > BCAP) c = BCAP;
    l[t] = c;
    __syncthreads();
    for (int off = 1; off < 256; off <<= 1) {
        int v = l[t] + ((t >= off) ? l[t - off] : 0);
        __syncthreads();
        l[t] = v;
        __syncthreads();
    }
    bucketBase[t] = l[t] - c;                          // exclusive
}

// ---- per-bucket LDS counting sort with (node, src-range) keys ----
// writes rp2 slice (4 keys/node), dinv, col (sorted by dst, then src-range)
__global__ __launch_bounds__(FB) void fill_k(const unsigned* __restrict__ bEdges,
                                             const int* __restrict__ bucketCnt,
                                             const int* __restrict__ bucketBase,
                                             int* __restrict__ rp2,
                                             float* __restrict__ dinv,
                                             int* __restrict__ col) {
    __shared__ int cur[GROUP_SZ * 4];      // 1564 key cursors
    __shared__ int nodesum[512];
    __shared__ unsigned lout[BCAP];        // 55.3 KB staging
    int b = blockIdx.x, t = threadIdx.x;
    int colBase = bucketBase[b];

    int nb = N_NODES - b * GROUP_SZ; if (nb > GROUP_SZ) nb = GROUP_SZ;
    int nk = nb * 4;
    for (int k = t; k < nk; k += FB) cur[k] = 0;
    __syncthreads();

    int cnt = bucketCnt[b]; if (cnt > BCAP) cnt = BCAP;
    const unsigned* be = bEdges + (size_t)b * BCAP;
    unsigned val[FILL_ITER];
#pragma unroll
    for (int i = 0; i < FILL_ITER; ++i) {
        int idx = i * FB + t;
        val[i] = 0xFFFFFFFFu;
        if (idx < cnt) {
            unsigned v = __builtin_nontemporal_load(be + idx);
            val[i] = v;
            unsigned key = (v >> 17) * NRANGE + (v & 0x1FFFFu) / RANGE_SZ;
            atomicAdd(&cur[key], 1);                   // LDS histogram
        }
    }
    __syncthreads();

    int h0 = 0, h1 = 0, h2 = 0, h3 = 0;
    if (t < nb) {
        h0 = cur[t * 4]; h1 = cur[t * 4 + 1]; h2 = cur[t * 4 + 2]; h3 = cur[t * 4 + 3];
        int dsum = h0 + h1 + h2 + h3;
        nodesum[t] = dsum;
        dinv[b * GROUP_SZ + t] = rsqrtf((float)(dsum + 1));
    } else if (t < 512) nodesum[t] = 0;
    __syncthreads();
    for (int off = 1; off < 512; off <<= 1) {
        int v = 0;
        if (t < 512) v = nodesum[t] + ((t >= off) ? nodesum[t - off] : 0);
        __syncthreads();
        if (t < 512) nodesum[t] = v;
        __syncthreads();
    }
    if (t < nb) {
        int p0 = (t > 0) ? nodesum[t - 1] : 0;
        int p1 = p0 + h0, p2 = p1 + h1, p3 = p2 + h2;
        int kb = (b * GROUP_SZ + t) * 4;
        int4 w; w.x = colBase + p0; w.y = colBase + p1; w.z = colBase + p2; w.w = colBase + p3;
        *(int4*)(rp2 + kb) = w;
        cur[t * 4] = p0; cur[t * 4 + 1] = p1; cur[t * 4 + 2] = p2; cur[t * 4 + 3] = p3;
    }
    __syncthreads();

#pragma unroll
    for (int i = 0; i < FILL_ITER; ++i) {
        unsigned v = val[i];
        if (v != 0xFFFFFFFFu) {
            unsigned key = (v >> 17) * NRANGE + (v & 0x1FFFFu) / RANGE_SZ;
            int slot = atomicAdd(&cur[key], 1);
            lout[slot] = v & 0x1FFFFu;
        }
    }
    __syncthreads();

    for (int i = t; i < cnt; i += FB)
        __builtin_nontemporal_store((int)lout[i], col + colBase + i);
}

// ---- layer 0 transform, register-blocked: thread = (8-node group, channel quad) ----
__global__ __launch_bounds__(256) void transform0_k(const float* __restrict__ x,
                                                    const float* __restrict__ W0,
                                                    const float* __restrict__ dinv,
                                                    float4* __restrict__ tmp4) {
    int i = blockIdx.x * blockDim.x + threadIdx.x;   // 100000 threads
    if (i >= (N_NODES / 8) * 8) return;
    int gid = i >> 3, q = i & 7;
    int n0 = gid * 8;
    const float* wq = W0 + q * 4;
    float4 acc[8];
#pragma unroll
    for (int j = 0; j < 8; ++j) acc[j] = make_float4(0.f, 0.f, 0.f, 0.f);
#pragma unroll 2
    for (int kc = 0; kc < F_IN / 4; ++kc) {
        float4 w0 = *(const float4*)(wq + (kc * 4 + 0) * EMB);
        float4 w1 = *(const float4*)(wq + (kc * 4 + 1) * EMB);
        float4 w2 = *(const float4*)(wq + (kc * 4 + 2) * EMB);
        float4 w3 = *(const float4*)(wq + (kc * 4 + 3) * EMB);
#pragma unroll
        for (int j = 0; j < 8; ++j) {
            float4 xv = *(const float4*)(x + (long long)(n0 + j) * F_IN + kc * 4);
            acc[j].x += xv.x * w0.x; acc[j].y += xv.x * w0.y; acc[j].z += xv.x * w0.z; acc[j].w += xv.x * w0.w;
            acc[j].x += xv.y * w1.x; acc[j].y += xv.y * w1.y; acc[j].z += xv.y * w1.z; acc[j].w += xv.y * w1.w;
            acc[j].x += xv.z * w2.x; acc[j].y += xv.z * w2.y; acc[j].z += xv.z * w2.z; acc[j].w += xv.z * w2.w;
            acc[j].x += xv.w * w3.x; acc[j].y += xv.w * w3.y; acc[j].z += xv.w * w3.z; acc[j].w += xv.w * w3.w;
        }
    }
#pragma unroll
    for (int j = 0; j < 8; ++j) {
        float dn = dinv[n0 + j];
        acc[j].x *= dn; acc[j].y *= dn; acc[j].z *= dn; acc[j].w *= dn;
        tmp4[(n0 + j) * 8 + q] = acc[j];
    }
}

// ---- fused gather: 4 src-range phases (L2 slice locality) + optional transform ----
// FUSE=1: out4 = (leaky(agg*dinv+bias) @ W) * dinv    FUSE=0: out4 = leaky(agg*dinv+bias)
template <bool FUSE>
__global__ __launch_bounds__(256) void gather_k(const int* __restrict__ rp2,
                                                const int* __restrict__ col,
                                                const float4* __restrict__ tmp4,
                                                const float* __restrict__ dinv,
                                                const float* __restrict__ bias,
                                                const float* __restrict__ W,
                                                float4* __restrict__ out4) {
    __shared__ float4 Wl[256];        // W[32][32] as [k*8+q]
    __shared__ float4 hx[32 * 9];     // 32 nodes x 8 quads, padded row=9
    int t = threadIdx.x;
    int i = blockIdx.x * 256 + t;     // grid exact: 3125 blocks
    int n = i >> 3, q = i & 7, ln = t >> 3;
    if (FUSE) {
        Wl[t] = ((const float4*)W)[t];
        __syncthreads();              // cheap start barrier for cross-wave Wl reads
    }

    int4 rpv = *(const int4*)(rp2 + n * 4);
    int rp4  = rp2[n * 4 + 4];
    int begs[5] = {rpv.x, rpv.y, rpv.z, rpv.w, rp4};

    float4 acc = tmp4[i];             // self-loop term
#pragma unroll
    for (int r = 0; r < NRANGE; ++r) {
        int k = begs[r], end = begs[r + 1];
        for (; k < end && (k & 3); ++k) {           // align to 16B (k-ascending)
            float4 v = tmp4[col[k] * 8 + q];
            acc.x += v.x; acc.y += v.y; acc.z += v.z; acc.w += v.w;
        }
        for (; k + 4 <= end; k += 4) {
            int4 c0 = *(const int4*)(col + k);
            float4 v0 = tmp4[c0.x * 8 + q], v1 = tmp4[c0.y * 8 + q];
            float4 v2 = tmp4[c0.z * 8 + q], v3 = tmp4[c0.w * 8 + q];
            acc.x += (v0.x + v1.x) + (v2.x + v3.x);
            acc.y += (v0.y + v1.y) + (v2.y + v3.y);
            acc.z += (v0.z + v1.z) + (v2.z + v3.z);
            acc.w += (v0.w + v1.w) + (v2.w + v3.w);
        }
        for (; k < end; ++k) {
            float4 v = tmp4[col[k] * 8 + q];
            acc.x += v.x; acc.y += v.y; acc.z += v.z; acc.w += v.w;
        }
    }
    float dn = dinv[n];
    float4 bb = ((const float4*)bias)[q];
    float4 rr;
    rr.x = acc.x * dn + bb.x;
    rr.y = acc.y * dn + bb.y;
    rr.z = acc.z * dn + bb.z;
    rr.w = acc.w * dn + bb.w;
    rr.x = rr.x > 0.f ? rr.x : 0.01f * rr.x;
    rr.y = rr.y > 0.f ? rr.y : 0.01f * rr.y;
    rr.z = rr.z > 0.f ? rr.z : 0.01f * rr.z;
    rr.w = rr.w > 0.f ? rr.w : 0.01f * rr.w;

    if (!FUSE) {
        out4[i] = rr;
        return;
    }
    // wave-synchronous h-exchange (lanes ln*8..ln*8+7 are intra-wave)
    hx[ln * 9 + q] = rr;
    __builtin_amdgcn_wave_barrier();
    float4 tq = make_float4(0.f, 0.f, 0.f, 0.f);
#pragma unroll
    for (int kq = 0; kq < 8; ++kq) {
        float4 hv = hx[ln * 9 + kq];
        float4 w0 = Wl[(kq * 4 + 0) * 8 + q];
        float4 w1 = Wl[(kq * 4 + 1) * 8 + q];
        float4 w2 = Wl[(kq * 4 + 2) * 8 + q];
        float4 w3 = Wl[(kq * 4 + 3) * 8 + q];
        tq.x += hv.x * w0.x; tq.y += hv.x * w0.y; tq.z += hv.x * w0.z; tq.w += hv.x * w0.w;
        tq.x += hv.y * w1.x; tq.y += hv.y * w1.y; tq.z += hv.y * w1.z; tq.w += hv.y * w1.w;
        tq.x += hv.z * w2.x; tq.y += hv.z * w2.y; tq.z += hv.z * w2.z; tq.w += hv.z * w2.w;
        tq.x += hv.w * w3.x; tq.y += hv.w * w3.y; tq.z += hv.w * w3.z; tq.w += hv.w * w3.w;
    }
    tq.x *= dn; tq.y *= dn; tq.z *= dn; tq.w *= dn;
    out4[i] = tq;
}

// ---- fused pool + head (batch_index sorted) ----
__global__ __launch_bounds__(256) void pool_head_k(const float* __restrict__ h,
                                                   const int* __restrict__ batch,
                                                   const float* __restrict__ Wout,
                                                   const float* __restrict__ bout,
                                                   float* __restrict__ out) {
    int g = blockIdx.x;
    __shared__ int sbeg, send;
    if (threadIdx.x == 0) {
        int lo = 0, hi = N_NODES;
        while (lo < hi) { int mid = (lo + hi) >> 1; if (batch[mid] < g) lo = mid + 1; else hi = mid; }
        sbeg = lo;
        hi = N_NODES;
        while (lo < hi) { int mid = (lo + hi) >> 1; if (batch[mid] < g + 1) lo = mid + 1; else hi = mid; }
        send = lo;
    }
    __syncthreads();
    int beg = sbeg, end = send;
    int t = threadIdx.x, c = t & 31, r = t >> 5;
    float m = -INFINITY;
    for (int n = beg + r; n < end; n += 8) m = fmaxf(m, h[n * EMB + c]);
    __shared__ float red[256];
    red[t] = m;
    __syncthreads();
    if (t < 128) red[t] = fmaxf(red[t], red[t + 128]);
    __syncthreads();
    if (t < 64) red[t] = fmaxf(red[t], red[t + 64]);
    __syncthreads();
    if (t < 32) {
        m = fmaxf(red[t], red[t + 32]);
        out[NUM_GRAPHS + g * EMB + c] = m;
        float p = m * Wout[c];
#pragma unroll
        for (int o = 16; o > 0; o >>= 1) p += __shfl_xor(p, o, 32);
        if (c == 0) out[g] = p + bout[0];
    }
}

extern "C" void kernel_launch(void* const* d_in, const int* in_sizes, int n_in,
                              void* d_out, int out_size, void* d_ws, size_t ws_size,
                              hipStream_t stream) {
    const float* x     = (const float*)d_in[0];
    const int*   ei    = (const int*)d_in[1];
    const int*   src   = ei;
    const int*   dst   = ei + N_EDGES;
    const int*   batch = (const int*)d_in[2];
    const float* W0    = (const float*)d_in[3];
    const float* b0    = (const float*)d_in[4];
    const float* Ws    = (const float*)d_in[5];
    const float* bs    = (const float*)d_in[6];
    const float* Wout  = (const float*)d_in[7];
    const float* bout  = (const float*)d_in[8];
    float* out = (float*)d_out;

    char* ws = (char*)d_ws;
    int*   rp2       = (int*)ws;   ws += (size_t)(NKEY + 4) * 4;        // 1.6 MB
    int*   col       = (int*)ws;   ws += (size_t)N_EDGES * 4;           // 12.8 MB
    float* dinv      = (float*)ws; ws += (size_t)N_NODES * 4;           // 400 KB
    float* tmp       = (float*)ws; ws += (size_t)N_NODES * EMB * 4;     // 12.8 MB
    float* h         = (float*)ws; ws += (size_t)N_NODES * EMB * 4;     // 12.8 MB
    int*   bucketCnt = (int*)ws;   ws += 1024;                          // 256 ints
    int*   bucketBase= (int*)ws;   ws += 1024;                          // 256 ints
    unsigned* bEdges = (unsigned*)tmp;   // 14.2 MB alias over tmp+h, dead before transforms

    const int B = 256;
    const int G8_g = (N_NODES * 8) / B;                  // 3125 exact
    const int T_g  = (N_NODES + B - 1) / B;              // 391

    init_k<<<1, B, 0, stream>>>(bucketCnt, rp2);
    partition_k<<<PART_NB, PART_THREADS, 0, stream>>>(src, dst, bucketCnt, bEdges);
    bucketbase_k<<<1, 256, 0, stream>>>(bucketCnt, bucketBase);
    fill_k<<<NGROUP, FB, 0, stream>>>(bEdges, bucketCnt, bucketBase, rp2, dinv, col);

    // layer 0 transform
    transform0_k<<<T_g, B, 0, stream>>>(x, W0, dinv, (float4*)tmp);
    // gathers: layers 0..2 fuse the next transform; layer 3 writes activations only
    gather_k<true ><<<G8_g, B, 0, stream>>>(rp2, col, (const float4*)tmp, dinv, b0,           Ws + 0 * 1024, (float4*)h);
    gather_k<true ><<<G8_g, B, 0, stream>>>(rp2, col, (const float4*)h,   dinv, bs + 0 * EMB, Ws + 1 * 1024, (float4*)tmp);
    gather_k<true ><<<G8_g, B, 0, stream>>>(rp2, col, (const float4*)tmp, dinv, bs + 1 * EMB, Ws + 2 * 1024, (float4*)h);
    gather_k<false><<<G8_g, B, 0, stream>>>(rp2, col, (const float4*)h,   dinv, bs + 2 * EMB, nullptr,       (float4*)tmp);

    pool_head_k<<<NUM_GRAPHS, B, 0, stream>>>(tmp, batch, Wout, bout, out);
}